// Round 9
// baseline (270.099 us; speedup 1.0000x reference)
//
#include <hip/hip_runtime.h>
#include <hip/hip_bf16.h>

#define N_NODES 50000
#define E_EDGES 800000
#define HID 128
#define HEADS 4
#define NEG_SLOPE 0.2f
#define LN_EPS 1e-5f
#define PARAM_FLOATS 17024  // [W region](16384) al(128) ar(128) b(128) g(128) be(128)
#define NBUCK 196           // buckets of 256 nodes
#define BCAP 6144           // max edges/bucket
#define BIN_CH 2048         // edges per bin block
#define CVT_BLOCKS 67       // ceil(PARAM_FLOATS/256)
#define GEMM_BLOCKS 782     // ceil(N_NODES/64)
#define BIN_BLOCKS 391      // ceil(E_EDGES/BIN_CH)
#define CL 16               // 64-B cache-line stride (in ints) for contended atomics

typedef __attribute__((ext_vector_type(8))) short short8;
typedef __attribute__((ext_vector_type(4))) float float4v;
typedef __fp16 hf2 __attribute__((ext_vector_type(2)));

__device__ __forceinline__ float bf2f(__hip_bfloat16 b) { return __bfloat162float(b); }
__device__ __forceinline__ short bfb(float f) {
    __hip_bfloat16 h = __float2bfloat16(f);
    return *(short*)&h;
}
__device__ __forceinline__ float leaky(float v) { return v > 0.f ? v : v * NEG_SLOPE; }

__device__ __forceinline__ unsigned int f2ord(float f) {
    unsigned int u = __float_as_uint(f);
    return (u & 0x80000000u) ? ~u : (u | 0x80000000u);
}
__device__ __forceinline__ float ord2f(unsigned int u) {
    u = (u & 0x80000000u) ? (u & 0x7FFFFFFFu) : ~u;
    return __uint_as_float(u);
}

// (a.lo16, b.lo16) and (a.hi16, b.hi16) 16-bit-pair helpers (1 v_perm_b32 each)
__device__ __forceinline__ unsigned int pair_lo(unsigned int a, unsigned int b) {
#if __has_builtin(__builtin_amdgcn_perm)
    return __builtin_amdgcn_perm(b, a, 0x05040100);
#else
    return (a & 0xFFFFu) | (b << 16);
#endif
}
__device__ __forceinline__ unsigned int pair_hi(unsigned int a, unsigned int b) {
#if __has_builtin(__builtin_amdgcn_perm)
    return __builtin_amdgcn_perm(b, a, 0x07060302);
#else
    return (a >> 16) | (b & 0xFFFF0000u);
#endif
}
// fused fp16 dot2-accumulate: acc += h.x*e.x + h.y*e.y  (v_dot2_f32_f16)
__device__ __forceinline__ float dot2acc(unsigned int hpair, unsigned int epair, float acc) {
#if __has_builtin(__builtin_amdgcn_fdot2)
    return __builtin_amdgcn_fdot2(__builtin_bit_cast(hf2, hpair),
                                  __builtin_bit_cast(hf2, epair), acc, false);
#else
    hf2 hv = __builtin_bit_cast(hf2, hpair);
    hf2 ev = __builtin_bit_cast(hf2, epair);
    return fmaf((float)hv.x, (float)ev.x, fmaf((float)hv.y, (float)ev.y, acc));
#endif
}
__device__ __forceinline__ unsigned int pk_f16x2(float a, float b) {
#if __has_builtin(__builtin_amdgcn_cvt_pkrtz)
    auto r = __builtin_amdgcn_cvt_pkrtz(a, b);
    return __builtin_bit_cast(unsigned int, r);
#else
    hf2 r = { (__fp16)a, (__fp16)b };
    return __builtin_bit_cast(unsigned int, r);
#endif
}

// ---------- merged: dtype detect (per-block, redundant) + param cvt for BOTH layers
// + one-time inits (flag, gmax, bcnt) in block 0.
__global__ __launch_bounds__(256) void cvt_params_kernel(
    const void* W0, const void* al0, const void* ar0, const void* b0,
    const void* g0, const void* be0,
    const void* W1, const void* al1, const void* ar1, const void* b1,
    const void* g1, const void* be1,
    float* __restrict__ out0, float* __restrict__ out1,
    unsigned short* __restrict__ wt0, unsigned short* __restrict__ wt1,
    unsigned int* __restrict__ flag, unsigned int* __restrict__ gmax0,
    unsigned int* __restrict__ gmax1, int* __restrict__ bcnt) {
    int t = threadIdx.x;
    // block-local bf16 detection on W0's first 4096 dwords (16 KB, L2-hot)
    const unsigned int* w0p = (const unsigned int*)W0;
    int cnt = 0;
    for (int i = t; i < 4096; i += 256) {
        unsigned int lo = (w0p[i] & 0xFFFFu) << 16;
        float v = fabsf(__uint_as_float(lo));
        if (v >= 1e-6f && v <= 1.0f) cnt++;
    }
#pragma unroll
    for (int off = 32; off >= 1; off >>= 1) cnt += __shfl_xor(cnt, off);
    __shared__ int shm[4];
    if ((t & 63) == 0) shm[t >> 6] = cnt;
    __syncthreads();
    unsigned int isb = ((shm[0] + shm[1] + shm[2] + shm[3]) > 2048) ? 1u : 0u;

    if (blockIdx.x == 0) {
        if (t == 0) *flag = isb;
        if (t < 4) {
            gmax0[t * CL] = f2ord(-INFINITY);
            gmax1[t * CL] = f2ord(-INFINITY);
        }
        if (t < NBUCK) bcnt[t * CL] = 0;
    }

    int blk = blockIdx.x;
    int layer = 0;
    if (blk >= CVT_BLOCKS) { layer = 1; blk -= CVT_BLOCKS; }
    int i = blk * 256 + t;
    if (i >= PARAM_FLOATS) return;

    const void *W, *al, *ar, *b, *g, *be;
    float* out;
    unsigned short* wt;
    if (layer == 0) {
        W = W0; al = al0; ar = ar0; b = b0; g = g0; be = be0;
        out = out0; wt = wt0;
    } else {
        W = W1; al = al1; ar = ar1; b = b1; g = g1; be = be1;
        out = out1; wt = wt1;
    }

    if (i < 16384) {
        unsigned short bits;
        if (isb) bits = ((const unsigned short*)W)[i];
        else     { short s = bfb(((const float*)W)[i]); bits = (unsigned short)s; }
        wt[((i & 127) << 7) | (i >> 7)] = bits;  // Wt[n][k] = W[k][n]
        return;
    }
    const void* src; int off;
    if (i < 16512)      { src = al; off = i - 16384; }
    else if (i < 16640) { src = ar; off = i - 16512; }
    else if (i < 16768) { src = b;  off = i - 16640; }
    else if (i < 16896) { src = g;  off = i - 16768; }
    else                { src = be; off = i - 16896; }
    out[i] = isb ? bf2f(((const __hip_bfloat16*)src)[off]) : ((const float*)src)[off];
}

// ---------- bin body: bin edges by dst>>8, packed (src<<8)|(dst&255) ----------
// bcnt padded to one counter per 64-B line: per-LINE atomic serialization at the
// L2 atomic unit was the suspected ~20 us cost (391 blocks x 196 adds on 13 lines).
__device__ void bin_body(void* smem_raw, const int* __restrict__ src,
                         const int* __restrict__ dst, int* __restrict__ bcnt,
                         unsigned int* __restrict__ ebuf, int bx) {
    int* lh = (int*)smem_raw;            // NBUCK ints
    int* lbase = lh + NBUCK;             // NBUCK ints
    int t = threadIdx.x;
    for (int i = t; i < NBUCK; i += 256) lh[i] = 0;
    __syncthreads();
    int e0 = bx * BIN_CH;
    int n = min(BIN_CH, E_EDGES - e0);
    int s8[8], d8[8], rk[8];
#pragma unroll
    for (int j = 0; j < 8; ++j) {
        int k = j * 256 + t;
        if (k < n) {
            s8[j] = src[e0 + k];
            d8[j] = dst[e0 + k];
            rk[j] = atomicAdd(&lh[d8[j] >> 8], 1);
        }
    }
    __syncthreads();
    for (int i = t; i < NBUCK; i += 256) lbase[i] = atomicAdd(&bcnt[i * CL], lh[i]);
    __syncthreads();
#pragma unroll
    for (int j = 0; j < 8; ++j) {
        int k = j * 256 + t;
        if (k < n) {
            int b = d8[j] >> 8;
            int pos = lbase[b] + rk[j];
            if (pos < BCAP)
                ebuf[b * BCAP + pos] = ((unsigned int)s8[j] << 8) | (unsigned int)(d8[j] & 255);
        }
    }
}

// ---------- CSR phase 2: bucket-base scan folded in ----------
__global__ __launch_bounds__(256) void csr_kernel(const int* __restrict__ bcnt,
                                                  const unsigned int* __restrict__ ebuf,
                                                  int* __restrict__ offs,
                                                  int* __restrict__ esrc) {
    __shared__ int cnt[256];
    __shared__ int wt[4];
    __shared__ int sbase[256];
    __shared__ int out_lds[BCAP];
    int b = blockIdx.x, t = threadIdx.x;
    int lane = t & 63, wid = t >> 6;

    // exclusive prefix over min(bcnt[i],BCAP) for all buckets (cheap, 196 ints)
    int bv = (t < NBUCK) ? min(bcnt[t * CL], BCAP) : 0;
    {
        int x = bv;
#pragma unroll
        for (int o = 1; o < 64; o <<= 1) {
            int y = __shfl_up(x, o);
            if (lane >= o) x += y;
        }
        if (lane == 63) wt[wid] = x;
        __syncthreads();
        int add = 0;
        for (int j = 0; j < wid; j++) add += wt[j];
        sbase[t] = add + x - bv;
    }
    __syncthreads();
    int base = sbase[b];
    int n = min(bcnt[b * CL], BCAP);
    const unsigned int* eb = ebuf + b * BCAP;
    cnt[t] = 0;
    __syncthreads();
    for (int i = t; i < n; i += 256) atomicAdd(&cnt[eb[i] & 255u], 1);
    __syncthreads();
    int v = cnt[t];
    int x = v;
#pragma unroll
    for (int o = 1; o < 64; o <<= 1) {
        int y = __shfl_up(x, o);
        if (lane >= o) x += y;
    }
    if (lane == 63) wt[wid] = x;
    __syncthreads();
    int add = 0;
    for (int j = 0; j < wid; j++) add += wt[j];
    int excl = add + x - v;
    int node = b * 256 + t;
    if (node <= N_NODES) offs[node] = base + excl;
    __syncthreads();
    cnt[t] = excl;
    __syncthreads();
    for (int i = t; i < n; i += 256) {
        unsigned int e = eb[i];
        int p = atomicAdd(&cnt[e & 255u], 1);
        out_lds[p] = (int)(e >> 8);
    }
    __syncthreads();
    for (int i = t; i < n; i += 256) esrc[base + i] = out_lds[i];
}

// ---------- MFMA GEMM body: h = x @ W -> fp16-packed h, el/er, per-head el-max ----------
__device__ void gemm_body(void* smem_raw, const void* __restrict__ xin,
                          const unsigned short* __restrict__ wt,
                          const float* __restrict__ params,
                          const unsigned int* __restrict__ flag, int mode,
                          unsigned int* __restrict__ hh, float* __restrict__ el,
                          float* __restrict__ er, unsigned int* __restrict__ gmax,
                          int M, int bx) {
    float (*ldsC)[16][132] = (float (*)[16][132])smem_raw;          // 4*16*132*4 B
    unsigned int* smax = (unsigned int*)((char*)smem_raw + 33792);  // 4 uints
    unsigned int isb = mode ? 1u : *flag;
    int t = threadIdx.x;
    if (t < 4) smax[t] = 0u;
    int w = t >> 6, lane = t & 63;
    int m = lane & 15, quad = lane >> 4;
    int row0b = bx * 64;
    int arow = row0b + w * 16 + m;
    bool avalid = arow < M;

    float4v acc[8];
#pragma unroll
    for (int i = 0; i < 8; i++) acc[i] = (float4v){0.f, 0.f, 0.f, 0.f};

#pragma unroll
    for (int kt = 0; kt < 4; ++kt) {
        short8 a = (short8){0, 0, 0, 0, 0, 0, 0, 0};
        if (avalid) {
            int base = arow * 128 + kt * 32 + quad * 8;
            if (isb) {
                a = *(const short8*)((const unsigned short*)xin + base);
            } else {
                const float* xp = (const float*)xin + base;
                float4 f0 = *(const float4*)xp;
                float4 f1 = *(const float4*)(xp + 4);
                a = (short8){bfb(f0.x), bfb(f0.y), bfb(f0.z), bfb(f0.w),
                             bfb(f1.x), bfb(f1.y), bfb(f1.z), bfb(f1.w)};
            }
        }
#pragma unroll
        for (int ct = 0; ct < 8; ++ct) {
            short8 b = *(const short8*)(wt + (ct * 16 + m) * 128 + kt * 32 + quad * 8);
            acc[ct] = __builtin_amdgcn_mfma_f32_16x16x32_bf16(a, b, acc[ct], 0, 0, 0);
        }
    }

#pragma unroll
    for (int ct = 0; ct < 8; ++ct)
#pragma unroll
        for (int r = 0; r < 4; ++r)
            ldsC[w][quad * 4 + r][ct * 16 + m] = acc[ct][r];
    __syncthreads();

    int c0 = (t & 15) * 8;
    int r0e = (t >> 4) * 4;
    float al8[8], ar8[8];
#pragma unroll
    for (int j = 0; j < 8; j++) {
        al8[j] = params[16384 + c0 + j];
        ar8[j] = params[16512 + c0 + j];
    }
    int head = (lane & 15) >> 2;
    float elmax = -INFINITY;

#pragma unroll
    for (int i = 0; i < 4; i++) {
        int rr = r0e + i;
        int row = row0b + rr;
        bool ok = row < M;
        const float* ld = &ldsC[rr >> 4][rr & 15][c0];
        float4 h0 = *(const float4*)ld;
        float4 h1 = *(const float4*)(ld + 4);
        float hv[8] = {h0.x, h0.y, h0.z, h0.w, h1.x, h1.y, h1.z, h1.w};
        if (ok) {
            unsigned int u0 = pk_f16x2(hv[0], hv[1]);
            unsigned int u1 = pk_f16x2(hv[2], hv[3]);
            unsigned int u2 = pk_f16x2(hv[4], hv[5]);
            unsigned int u3 = pk_f16x2(hv[6], hv[7]);
            *(uint4*)(hh + row * 64 + (c0 >> 1)) = make_uint4(u0, u1, u2, u3);
        }
        float e_l = 0.f, e_r = 0.f;
#pragma unroll
        for (int j = 0; j < 8; j++) {
            e_l = fmaf(hv[j], al8[j], e_l);
            e_r = fmaf(hv[j], ar8[j], e_r);
        }
        e_l += __shfl_xor(e_l, 1); e_l += __shfl_xor(e_l, 2);
        e_r += __shfl_xor(e_r, 1); e_r += __shfl_xor(e_r, 2);
        if (ok && (lane & 3) == 0) {
            el[row * 4 + head] = e_l;
            er[row * 4 + head] = e_r;
            elmax = fmaxf(elmax, e_l);
        }
    }
    elmax = fmaxf(elmax, __shfl_xor(elmax, 16));
    elmax = fmaxf(elmax, __shfl_xor(elmax, 32));
    __syncthreads();
    if ((lane & 15) == 0 || (lane & 15) == 4 || (lane & 15) == 8 || (lane & 15) == 12) {
        if (elmax > -INFINITY) atomicMax(&smax[head], f2ord(elmax));
    }
    __syncthreads();
    // gmax padded to one counter per 64-B line (782 blocks previously hammered 1 line)
    if (t < 4) atomicMax(&gmax[t * CL], smax[t]);
}

// ---------- fused: gemm layer-1 (blocks [0,GEMM_BLOCKS)) + edge bin (rest) ----------
__global__ __launch_bounds__(256) void gemm1_bin_kernel(
    const void* __restrict__ xin, const unsigned short* __restrict__ wt,
    const float* __restrict__ params, const unsigned int* __restrict__ flag,
    unsigned int* __restrict__ hh, float* __restrict__ el, float* __restrict__ er,
    unsigned int* __restrict__ gmax,
    const int* __restrict__ esrc_in, const int* __restrict__ edst_in,
    int* __restrict__ bcnt, unsigned int* __restrict__ ebuf) {
    __shared__ __align__(16) char smem[33808];
    if (blockIdx.x < GEMM_BLOCKS) {
        gemm_body(smem, xin, wt, params, flag, 0, hh, el, er, gmax, N_NODES, blockIdx.x);
    } else {
        bin_body(smem, esrc_in, edst_in, bcnt, ebuf, blockIdx.x - GEMM_BLOCKS);
    }
}

__global__ __launch_bounds__(256) void gemm_kernel(
    const void* __restrict__ xin, const unsigned short* __restrict__ wt,
    const float* __restrict__ params, const unsigned int* __restrict__ flag,
    int mode, unsigned int* __restrict__ hh, float* __restrict__ el,
    float* __restrict__ er, unsigned int* __restrict__ gmax, int M) {
    __shared__ __align__(16) char smem[33808];
    gemm_body(smem, xin, wt, params, flag, mode, hh, el, er, gmax, M, blockIdx.x);
}

// ---------- fused: single-pass (bounded-max) softmax agg + bias + LN + ELU ----------
// R6 body (best measured): quarter-wave edge split + fp16 h + edge-paired
// v_dot2_f32_f16. Three structural variants (R3/R6/R7) all land ~43 us —
// bound by the hh row-gather itself, so this is kept as-is.
template <bool LAST>
__global__ __launch_bounds__(256) void agg_ln_kernel(const int* __restrict__ offs,
                                                     const int* __restrict__ esrc,
                                                     const float* __restrict__ el,
                                                     const float* __restrict__ er,
                                                     const unsigned int* __restrict__ hh,
                                                     const float* __restrict__ params,
                                                     const unsigned int* __restrict__ gmax,
                                                     const unsigned int* __restrict__ flag,
                                                     unsigned int* __restrict__ x_next,
                                                     void* __restrict__ out) {
    int node = (blockIdx.x * 256 + threadIdx.x) >> 6;
    int lane = threadIdx.x & 63;
    if (node >= N_NODES) return;
    int e0 = offs[node], e1 = offs[node + 1];
    int d = e1 - e0;
    // producer role: slot loads edge b0+slot for head sh
    int sh = lane & 3;
    int slot = lane >> 2;
    // consumer role: quarter q handles edge-slots {q,4+q,8+q,12+q}; lane owns cols [l4*8, l4*8+8)
    int q = lane >> 4;
    int l4 = lane & 15;
    int hd = l4 >> 2;  // head of this lane's 8 columns
    float er_s = er[node * 4 + sh];
    float M = leaky(ord2f(gmax[sh * CL]) + er_s);

    float lsum = 0.f;
    float a0 = 0.f, a1 = 0.f, a2 = 0.f, a3 = 0.f;
    float a4 = 0.f, a5 = 0.f, a6 = 0.f, a7 = 0.f;
    for (int b0 = 0; b0 < d; b0 += 16) {
        int idx = b0 + slot;
        float ex = 0.f;
        int s = 0;
        if (idx < d) {
            s = esrc[e0 + idx];
            ex = __expf(leaky(el[s * 4 + sh] + er_s) - M);
        }
        lsum += ex;
        __fp16 e16 = (__fp16)ex;
        unsigned int pk = ((unsigned int)s << 16)
                        | (unsigned int)__builtin_bit_cast(unsigned short, e16);
        // invalid edge slots broadcast pk==(s=0, ex=0): row-0 load cache-hot, dot*0.
#pragma unroll
        for (int jp = 0; jp < 2; ++jp) {
            unsigned int q1 = __shfl(pk, (jp * 8 + q) * 4 + hd);
            unsigned int q2 = __shfl(pk, (jp * 8 + 4 + q) * 4 + hd);
            int s1 = (int)(q1 >> 16);
            int s2 = (int)(q2 >> 16);
            uint4 p = *(const uint4*)(hh + s1 * 64 + l4 * 4);
            uint4 r = *(const uint4*)(hh + s2 * 64 + l4 * 4);
            unsigned int e2 = pair_lo(q1, q2);  // (ex1, ex2) as fp16x2
            a0 = dot2acc(pair_lo(p.x, r.x), e2, a0);
            a1 = dot2acc(pair_hi(p.x, r.x), e2, a1);
            a2 = dot2acc(pair_lo(p.y, r.y), e2, a2);
            a3 = dot2acc(pair_hi(p.y, r.y), e2, a3);
            a4 = dot2acc(pair_lo(p.z, r.z), e2, a4);
            a5 = dot2acc(pair_hi(p.z, r.z), e2, a5);
            a6 = dot2acc(pair_lo(p.w, r.w), e2, a6);
            a7 = dot2acc(pair_hi(p.w, r.w), e2, a7);
        }
    }
#pragma unroll
    for (int off = 4; off <= 32; off <<= 1) lsum += __shfl_xor(lsum, off);
    float l = __shfl(lsum, hd);
    // combine the 4 quarters (after this, all quarters hold identical sums)
    a0 += __shfl_xor(a0, 16); a0 += __shfl_xor(a0, 32);
    a1 += __shfl_xor(a1, 16); a1 += __shfl_xor(a1, 32);
    a2 += __shfl_xor(a2, 16); a2 += __shfl_xor(a2, 32);
    a3 += __shfl_xor(a3, 16); a3 += __shfl_xor(a3, 32);
    a4 += __shfl_xor(a4, 16); a4 += __shfl_xor(a4, 32);
    a5 += __shfl_xor(a5, 16); a5 += __shfl_xor(a5, 32);
    a6 += __shfl_xor(a6, 16); a6 += __shfl_xor(a6, 32);
    a7 += __shfl_xor(a7, 16); a7 += __shfl_xor(a7, 32);

    float inv = 1.f / fmaxf(l, 1e-9f);
    int c0 = l4 * 8;
    float4 ba = *(const float4*)(params + 16640 + c0);
    float4 bb = *(const float4*)(params + 16640 + c0 + 4);
    float v0 = fmaf(a0, inv, ba.x);
    float v1 = fmaf(a1, inv, ba.y);
    float v2 = fmaf(a2, inv, ba.z);
    float v3 = fmaf(a3, inv, ba.w);
    float v4 = fmaf(a4, inv, bb.x);
    float v5 = fmaf(a5, inv, bb.y);
    float v6 = fmaf(a6, inv, bb.z);
    float v7 = fmaf(a7, inv, bb.w);

    // interleaved sum / sum-of-squares reduction over the 16-lane group
    float s1 = (v0 + v1) + (v2 + v3) + (v4 + v5) + (v6 + v7);
    float s2 = (v0 * v0 + v1 * v1) + (v2 * v2 + v3 * v3)
             + (v4 * v4 + v5 * v5) + (v6 * v6 + v7 * v7);
#pragma unroll
    for (int off = 1; off <= 8; off <<= 1) {
        s1 += __shfl_xor(s1, off);
        s2 += __shfl_xor(s2, off);
    }
    float mu = s1 * (1.f / 128.f);
    float var = fmaxf(s2 * (1.f / 128.f) - mu * mu, 0.f);
    float rstd = rsqrtf(var + LN_EPS);
    float4 ga = *(const float4*)(params + 16768 + c0);
    float4 gb = *(const float4*)(params + 16768 + c0 + 4);
    float4 ea = *(const float4*)(params + 16896 + c0);
    float4 eb = *(const float4*)(params + 16896 + c0 + 4);
    float y0 = (v0 - mu) * rstd * ga.x + ea.x;
    float y1 = (v1 - mu) * rstd * ga.y + ea.y;
    float y2 = (v2 - mu) * rstd * ga.z + ea.z;
    float y3 = (v3 - mu) * rstd * ga.w + ea.w;
    float y4 = (v4 - mu) * rstd * gb.x + eb.x;
    float y5 = (v5 - mu) * rstd * gb.y + eb.y;
    float y6 = (v6 - mu) * rstd * gb.z + eb.z;
    float y7 = (v7 - mu) * rstd * gb.w + eb.w;
    // ELU via exp(y)-1 (cancellation err ~1e-8, well under absmax budget)
    y0 = y0 > 0.f ? y0 : (__expf(y0) - 1.f);
    y1 = y1 > 0.f ? y1 : (__expf(y1) - 1.f);
    y2 = y2 > 0.f ? y2 : (__expf(y2) - 1.f);
    y3 = y3 > 0.f ? y3 : (__expf(y3) - 1.f);
    y4 = y4 > 0.f ? y4 : (__expf(y4) - 1.f);
    y5 = y5 > 0.f ? y5 : (__expf(y5) - 1.f);
    y6 = y6 > 0.f ? y6 : (__expf(y6) - 1.f);
    y7 = y7 > 0.f ? y7 : (__expf(y7) - 1.f);

    if (q == 0) {
        if (LAST && !*flag) {
            *(float4*)((float*)out + node * 128 + c0) = make_float4(y0, y1, y2, y3);
            *(float4*)((float*)out + node * 128 + c0 + 4) = make_float4(y4, y5, y6, y7);
        } else {
            uint4 pk4;
            pk4.x = (unsigned int)(unsigned short)bfb(y0)
                  | ((unsigned int)(unsigned short)bfb(y1) << 16);
            pk4.y = (unsigned int)(unsigned short)bfb(y2)
                  | ((unsigned int)(unsigned short)bfb(y3) << 16);
            pk4.z = (unsigned int)(unsigned short)bfb(y4)
                  | ((unsigned int)(unsigned short)bfb(y5) << 16);
            pk4.w = (unsigned int)(unsigned short)bfb(y6)
                  | ((unsigned int)(unsigned short)bfb(y7) << 16);
            unsigned int* dst = LAST ? (unsigned int*)out : x_next;
            *(uint4*)(dst + node * 64 + l4 * 4) = pk4;
        }
    }
}

extern "C" void kernel_launch(void* const* d_in, const int* in_sizes, int n_in,
                              void* d_out, int out_size, void* d_ws, size_t ws_size,
                              hipStream_t stream) {
    const void* features = d_in[0];
    const int* src = (const int*)d_in[1];
    const int* dst = (const int*)d_in[2];

    char* w = (char*)d_ws;
    unsigned int* xbuf = (unsigned int*)w;                 // 12.8 MB (layer-2 input, packed bf16)
    unsigned int* hh = (unsigned int*)(w + 12800000);      // 12.8 MB (h fp16 packed)
    float* el = (float*)(w + 25600000);                    // 800 KB
    float* er = (float*)(w + 26400000);                    // 800 KB
    float* params0 = (float*)(w + 27200000);               // 68 KB
    float* params1 = params0 + PARAM_FLOATS;               // 68 KB
    unsigned short* wt0 = (unsigned short*)(w + 27337000); // 32 KB
    unsigned short* wt1 = wt0 + 16384;                     // 32 KB
    int* offs = (int*)(w + 27403000);                      // 50001 ints
    int* esrc = (int*)(w + 27604000);                      // 800000 ints
    unsigned int* flag  = (unsigned int*)(w + 30806848);
    unsigned int* ebuf = (unsigned int*)(w + 30807040);    // 196*6144*4 = 4.8 MB
    int* bcnt  = (int*)(w + 36000000);                     // 196 * 16-int stride = 12.5 KB
    unsigned int* gmax0 = (unsigned int*)(w + 36100096);   // 4 * 16-uint stride
    unsigned int* gmax1 = (unsigned int*)(w + 36101120);   // 4 * 16-uint stride

    // K1: param cvt + one-time inits (flag, gmax, bcnt zero)
    cvt_params_kernel<<<2 * CVT_BLOCKS, 256, 0, stream>>>(
        d_in[3], d_in[4], d_in[5], d_in[6], d_in[7], d_in[8],
        d_in[9], d_in[10], d_in[11], d_in[12], d_in[13], d_in[14],
        params0, params1, wt0, wt1, flag, gmax0, gmax1, bcnt);

    // K2: gemm layer-1 fused with edge binning (independent work, one dispatch)
    gemm1_bin_kernel<<<GEMM_BLOCKS + BIN_BLOCKS, 256, 0, stream>>>(
        features, wt0, params0, flag, hh, el, er, gmax0, src, dst, bcnt, ebuf);

    // K3: CSR finalize
    csr_kernel<<<NBUCK, 256, 0, stream>>>(bcnt, ebuf, offs, esrc);

    // K4: agg+LN layer-1
    agg_ln_kernel<false><<<(N_NODES * 64 + 255) / 256, 256, 0, stream>>>(
        offs, esrc, el, er, hh, params0, gmax0, flag, xbuf, nullptr);

    // K5: gemm layer-2
    gemm_kernel<<<GEMM_BLOCKS, 256, 0, stream>>>(
        xbuf, wt1, params1, flag, 1, hh, el, er, gmax1, N_NODES);

    // K6: agg+LN layer-2 (writes final output)
    agg_ln_kernel<true><<<(N_NODES * 64 + 255) / 256, 256, 0, stream>>>(
        offs, esrc, el, er, hh, params1, gmax1, flag, nullptr, d_out);
}

// Round 10
// 255.160 us; speedup vs baseline: 1.0585x; 1.0585x over previous
//
#include <hip/hip_runtime.h>
#include <hip/hip_bf16.h>

#define N_NODES 50000
#define E_EDGES 800000
#define HID 128
#define HEADS 4
#define NEG_SLOPE 0.2f
#define LN_EPS 1e-5f
#define PARAM_FLOATS 17024  // [W region](16384) al(128) ar(128) b(128) g(128) be(128)
#define NBUCK 196           // buckets of 256 nodes
#define BCAP 6144           // max edges/bucket
#define BIN_CH 2048         // edges per bin block
#define CVT_BLOCKS 67       // ceil(PARAM_FLOATS/256)
#define GEMM_BLOCKS 782     // ceil(N_NODES/64)
#define BIN_BLOCKS 391      // ceil(E_EDGES/BIN_CH)
#define LDS_ROWSTRIDE 136   // ushorts; 272 B = 16-B aligned rows for b128 reads
#define LDS_BYTES (4 * 16 * LDS_ROWSTRIDE * 2)  // 17408

typedef __attribute__((ext_vector_type(8))) short short8;
typedef __attribute__((ext_vector_type(4))) float float4v;
typedef __fp16 hf2 __attribute__((ext_vector_type(2)));

__device__ __forceinline__ float bf2f(__hip_bfloat16 b) { return __bfloat162float(b); }
__device__ __forceinline__ short bfb(float f) {
    __hip_bfloat16 h = __float2bfloat16(f);
    return *(short*)&h;
}
__device__ __forceinline__ float leaky(float v) { return v > 0.f ? v : v * NEG_SLOPE; }

__device__ __forceinline__ unsigned int f2ord(float f) {
    unsigned int u = __float_as_uint(f);
    return (u & 0x80000000u) ? ~u : (u | 0x80000000u);
}
__device__ __forceinline__ float ord2f(unsigned int u) {
    u = (u & 0x80000000u) ? (u & 0x7FFFFFFFu) : ~u;
    return __uint_as_float(u);
}

// (a.lo16, b.lo16) and (a.hi16, b.hi16) 16-bit-pair helpers (1 v_perm_b32 each)
__device__ __forceinline__ unsigned int pair_lo(unsigned int a, unsigned int b) {
#if __has_builtin(__builtin_amdgcn_perm)
    return __builtin_amdgcn_perm(b, a, 0x05040100);
#else
    return (a & 0xFFFFu) | (b << 16);
#endif
}
__device__ __forceinline__ unsigned int pair_hi(unsigned int a, unsigned int b) {
#if __has_builtin(__builtin_amdgcn_perm)
    return __builtin_amdgcn_perm(b, a, 0x07060302);
#else
    return (a >> 16) | (b & 0xFFFF0000u);
#endif
}
// fused fp16 dot2-accumulate: acc += h.x*e.x + h.y*e.y  (v_dot2_f32_f16)
__device__ __forceinline__ float dot2acc(unsigned int hpair, unsigned int epair, float acc) {
#if __has_builtin(__builtin_amdgcn_fdot2)
    return __builtin_amdgcn_fdot2(__builtin_bit_cast(hf2, hpair),
                                  __builtin_bit_cast(hf2, epair), acc, false);
#else
    hf2 hv = __builtin_bit_cast(hf2, hpair);
    hf2 ev = __builtin_bit_cast(hf2, epair);
    return fmaf((float)hv.x, (float)ev.x, fmaf((float)hv.y, (float)ev.y, acc));
#endif
}
__device__ __forceinline__ unsigned int pk_f16x2(float a, float b) {
#if __has_builtin(__builtin_amdgcn_cvt_pkrtz)
    auto r = __builtin_amdgcn_cvt_pkrtz(a, b);
    return __builtin_bit_cast(unsigned int, r);
#else
    hf2 r = { (__fp16)a, (__fp16)b };
    return __builtin_bit_cast(unsigned int, r);
#endif
}

// ---------- merged: dtype detect (per-block, redundant) + param cvt for BOTH layers
// + one-time inits (flag, gmax, bcnt) in block 0.
__global__ __launch_bounds__(256) void cvt_params_kernel(
    const void* W0, const void* al0, const void* ar0, const void* b0,
    const void* g0, const void* be0,
    const void* W1, const void* al1, const void* ar1, const void* b1,
    const void* g1, const void* be1,
    float* __restrict__ out0, float* __restrict__ out1,
    unsigned short* __restrict__ wt0, unsigned short* __restrict__ wt1,
    unsigned int* __restrict__ flag, unsigned int* __restrict__ gmax0,
    unsigned int* __restrict__ gmax1, int* __restrict__ bcnt) {
    int t = threadIdx.x;
    // block-local bf16 detection on W0's first 4096 dwords (16 KB, L2-hot)
    const unsigned int* w0p = (const unsigned int*)W0;
    int cnt = 0;
    for (int i = t; i < 4096; i += 256) {
        unsigned int lo = (w0p[i] & 0xFFFFu) << 16;
        float v = fabsf(__uint_as_float(lo));
        if (v >= 1e-6f && v <= 1.0f) cnt++;
    }
#pragma unroll
    for (int off = 32; off >= 1; off >>= 1) cnt += __shfl_xor(cnt, off);
    __shared__ int shm[4];
    if ((t & 63) == 0) shm[t >> 6] = cnt;
    __syncthreads();
    unsigned int isb = ((shm[0] + shm[1] + shm[2] + shm[3]) > 2048) ? 1u : 0u;

    if (blockIdx.x == 0) {
        if (t == 0) *flag = isb;
        if (t < 4) {
            gmax0[t] = f2ord(-INFINITY);
            gmax1[t] = f2ord(-INFINITY);
        }
        if (t < NBUCK) bcnt[t] = 0;
    }

    int blk = blockIdx.x;
    int layer = 0;
    if (blk >= CVT_BLOCKS) { layer = 1; blk -= CVT_BLOCKS; }
    int i = blk * 256 + t;
    if (i >= PARAM_FLOATS) return;

    const void *W, *al, *ar, *b, *g, *be;
    float* out;
    unsigned short* wt;
    if (layer == 0) {
        W = W0; al = al0; ar = ar0; b = b0; g = g0; be = be0;
        out = out0; wt = wt0;
    } else {
        W = W1; al = al1; ar = ar1; b = b1; g = g1; be = be1;
        out = out1; wt = wt1;
    }

    if (i < 16384) {
        unsigned short bits;
        if (isb) bits = ((const unsigned short*)W)[i];
        else     { short s = bfb(((const float*)W)[i]); bits = (unsigned short)s; }
        wt[((i & 127) << 7) | (i >> 7)] = bits;  // Wt[n][k] = W[k][n]
        return;
    }
    const void* src; int off;
    if (i < 16512)      { src = al; off = i - 16384; }
    else if (i < 16640) { src = ar; off = i - 16512; }
    else if (i < 16768) { src = b;  off = i - 16640; }
    else if (i < 16896) { src = g;  off = i - 16768; }
    else                { src = be; off = i - 16896; }
    out[i] = isb ? bf2f(((const __hip_bfloat16*)src)[off]) : ((const float*)src)[off];
}

// ---------- bin body: bin edges by dst>>8, packed (src<<8)|(dst&255) ----------
__device__ void bin_body(void* smem_raw, const int* __restrict__ src,
                         const int* __restrict__ dst, int* __restrict__ bcnt,
                         unsigned int* __restrict__ ebuf, int bx) {
    int* lh = (int*)smem_raw;            // NBUCK ints
    int* lbase = lh + NBUCK;             // NBUCK ints
    int t = threadIdx.x;
    for (int i = t; i < NBUCK; i += 256) lh[i] = 0;
    __syncthreads();
    int e0 = bx * BIN_CH;
    int n = min(BIN_CH, E_EDGES - e0);
    int s8[8], d8[8], rk[8];
#pragma unroll
    for (int j = 0; j < 8; ++j) {
        int k = j * 256 + t;
        if (k < n) {
            s8[j] = src[e0 + k];
            d8[j] = dst[e0 + k];
            rk[j] = atomicAdd(&lh[d8[j] >> 8], 1);
        }
    }
    __syncthreads();
    for (int i = t; i < NBUCK; i += 256) lbase[i] = atomicAdd(&bcnt[i], lh[i]);
    __syncthreads();
#pragma unroll
    for (int j = 0; j < 8; ++j) {
        int k = j * 256 + t;
        if (k < n) {
            int b = d8[j] >> 8;
            int pos = lbase[b] + rk[j];
            if (pos < BCAP)
                ebuf[b * BCAP + pos] = ((unsigned int)s8[j] << 8) | (unsigned int)(d8[j] & 255);
        }
    }
}

// ---------- CSR phase 2: bucket-base scan folded in ----------
__global__ __launch_bounds__(256) void csr_kernel(const int* __restrict__ bcnt,
                                                  const unsigned int* __restrict__ ebuf,
                                                  int* __restrict__ offs,
                                                  int* __restrict__ esrc) {
    __shared__ int cnt[256];
    __shared__ int wt[4];
    __shared__ int sbase[256];
    __shared__ int out_lds[BCAP];
    int b = blockIdx.x, t = threadIdx.x;
    int lane = t & 63, wid = t >> 6;

    // exclusive prefix over min(bcnt[i],BCAP) for all buckets (cheap, 196 ints)
    int bv = (t < NBUCK) ? min(bcnt[t], BCAP) : 0;
    {
        int x = bv;
#pragma unroll
        for (int o = 1; o < 64; o <<= 1) {
            int y = __shfl_up(x, o);
            if (lane >= o) x += y;
        }
        if (lane == 63) wt[wid] = x;
        __syncthreads();
        int add = 0;
        for (int j = 0; j < wid; j++) add += wt[j];
        sbase[t] = add + x - bv;
    }
    __syncthreads();
    int base = sbase[b];
    int n = min(bcnt[b], BCAP);
    const unsigned int* eb = ebuf + b * BCAP;
    cnt[t] = 0;
    __syncthreads();
    for (int i = t; i < n; i += 256) atomicAdd(&cnt[eb[i] & 255u], 1);
    __syncthreads();
    int v = cnt[t];
    int x = v;
#pragma unroll
    for (int o = 1; o < 64; o <<= 1) {
        int y = __shfl_up(x, o);
        if (lane >= o) x += y;
    }
    if (lane == 63) wt[wid] = x;
    __syncthreads();
    int add = 0;
    for (int j = 0; j < wid; j++) add += wt[j];
    int excl = add + x - v;
    int node = b * 256 + t;
    if (node <= N_NODES) offs[node] = base + excl;
    __syncthreads();
    cnt[t] = excl;
    __syncthreads();
    for (int i = t; i < n; i += 256) {
        unsigned int e = eb[i];
        int p = atomicAdd(&cnt[e & 255u], 1);
        out_lds[p] = (int)(e >> 8);
    }
    __syncthreads();
    for (int i = t; i < n; i += 256) esrc[base + i] = out_lds[i];
}

// ---------- MFMA GEMM body: h = x @ W -> fp16-packed h, el/er, per-head el-max ----------
// Epilogue staging tile in fp16 (17.4 KB vs 33.8 KB f32): LDS no longer caps
// occupancy at 4 blocks/CU (R8 counters: occ 20%, MfmaUtil 1%, HBM 0.8 TB/s —
// pure latency-bound, 1173 blocks needing 2 residency rounds at 4/CU). At
// 6 blocks/CU (VGPR-limited) all blocks fit one round. Epilogue also gets
// cheaper: 1 ds_read_b128, hh store is a raw uint4 copy, el/er via fdot2.
__device__ void gemm_body(void* smem_raw, const void* __restrict__ xin,
                          const unsigned short* __restrict__ wt,
                          const float* __restrict__ params,
                          const unsigned int* __restrict__ flag, int mode,
                          unsigned int* __restrict__ hh, float* __restrict__ el,
                          float* __restrict__ er, unsigned int* __restrict__ gmax,
                          int M, int bx) {
    unsigned short (*ldsH)[16][LDS_ROWSTRIDE] =
        (unsigned short (*)[16][LDS_ROWSTRIDE])smem_raw;
    unsigned int* smax = (unsigned int*)((char*)smem_raw + LDS_BYTES);
    unsigned int isb = mode ? 1u : *flag;
    int t = threadIdx.x;
    if (t < 4) smax[t] = 0u;
    int w = t >> 6, lane = t & 63;
    int m = lane & 15, quad = lane >> 4;
    int row0b = bx * 64;
    int arow = row0b + w * 16 + m;
    bool avalid = arow < M;

    float4v acc[8];
#pragma unroll
    for (int i = 0; i < 8; i++) acc[i] = (float4v){0.f, 0.f, 0.f, 0.f};

#pragma unroll
    for (int kt = 0; kt < 4; ++kt) {
        short8 a = (short8){0, 0, 0, 0, 0, 0, 0, 0};
        if (avalid) {
            int base = arow * 128 + kt * 32 + quad * 8;
            if (isb) {
                a = *(const short8*)((const unsigned short*)xin + base);
            } else {
                const float* xp = (const float*)xin + base;
                float4 f0 = *(const float4*)xp;
                float4 f1 = *(const float4*)(xp + 4);
                a = (short8){bfb(f0.x), bfb(f0.y), bfb(f0.z), bfb(f0.w),
                             bfb(f1.x), bfb(f1.y), bfb(f1.z), bfb(f1.w)};
            }
        }
#pragma unroll
        for (int ct = 0; ct < 8; ++ct) {
            short8 b = *(const short8*)(wt + (ct * 16 + m) * 128 + kt * 32 + quad * 8);
            acc[ct] = __builtin_amdgcn_mfma_f32_16x16x32_bf16(a, b, acc[ct], 0, 0, 0);
        }
    }

    // stage C tile as fp16 (2 B/elem): lane owns col ct*16+m, rows quad*4+r
#pragma unroll
    for (int ct = 0; ct < 8; ++ct)
#pragma unroll
        for (int r = 0; r < 4; ++r) {
            __fp16 hv16 = (__fp16)acc[ct][r];
            ldsH[w][quad * 4 + r][ct * 16 + m] =
                __builtin_bit_cast(unsigned short, hv16);
        }
    __syncthreads();

    int c0 = (t & 15) * 8;
    int r0e = (t >> 4) * 4;
    // al/ar packed as fp16 pairs for fdot2
    unsigned int alp[4], arp[4];
#pragma unroll
    for (int j = 0; j < 4; j++) {
        alp[j] = pk_f16x2(params[16384 + c0 + 2 * j], params[16384 + c0 + 2 * j + 1]);
        arp[j] = pk_f16x2(params[16512 + c0 + 2 * j], params[16512 + c0 + 2 * j + 1]);
    }
    int head = (lane & 15) >> 2;
    float elmax = -INFINITY;

#pragma unroll
    for (int i = 0; i < 4; i++) {
        int rr = r0e + i;
        int row = row0b + rr;
        bool ok = row < M;
        const unsigned short* ld = &ldsH[rr >> 4][rr & 15][c0];
        uint4 hu = *(const uint4*)ld;  // 8 cols fp16-packed
        if (ok) {
            *(uint4*)(hh + row * 64 + (c0 >> 1)) = hu;  // straight copy
        }
        float e_l = 0.f, e_r = 0.f;
        e_l = dot2acc(hu.x, alp[0], e_l);
        e_l = dot2acc(hu.y, alp[1], e_l);
        e_l = dot2acc(hu.z, alp[2], e_l);
        e_l = dot2acc(hu.w, alp[3], e_l);
        e_r = dot2acc(hu.x, arp[0], e_r);
        e_r = dot2acc(hu.y, arp[1], e_r);
        e_r = dot2acc(hu.z, arp[2], e_r);
        e_r = dot2acc(hu.w, arp[3], e_r);
        e_l += __shfl_xor(e_l, 1); e_l += __shfl_xor(e_l, 2);
        e_r += __shfl_xor(e_r, 1); e_r += __shfl_xor(e_r, 2);
        if (ok && (lane & 3) == 0) {
            el[row * 4 + head] = e_l;
            er[row * 4 + head] = e_r;
            elmax = fmaxf(elmax, e_l);
        }
    }
    elmax = fmaxf(elmax, __shfl_xor(elmax, 16));
    elmax = fmaxf(elmax, __shfl_xor(elmax, 32));
    __syncthreads();
    if ((lane & 15) == 0 || (lane & 15) == 4 || (lane & 15) == 8 || (lane & 15) == 12) {
        if (elmax > -INFINITY) atomicMax(&smax[head], f2ord(elmax));
    }
    __syncthreads();
    if (t < 4) atomicMax(&gmax[t], smax[t]);
}

// ---------- fused: gemm layer-1 (blocks [0,GEMM_BLOCKS)) + edge bin (rest) ----------
__global__ __launch_bounds__(256) void gemm1_bin_kernel(
    const void* __restrict__ xin, const unsigned short* __restrict__ wt,
    const float* __restrict__ params, const unsigned int* __restrict__ flag,
    unsigned int* __restrict__ hh, float* __restrict__ el, float* __restrict__ er,
    unsigned int* __restrict__ gmax,
    const int* __restrict__ esrc_in, const int* __restrict__ edst_in,
    int* __restrict__ bcnt, unsigned int* __restrict__ ebuf) {
    __shared__ __align__(16) char smem[LDS_BYTES + 16];
    if (blockIdx.x < GEMM_BLOCKS) {
        gemm_body(smem, xin, wt, params, flag, 0, hh, el, er, gmax, N_NODES, blockIdx.x);
    } else {
        bin_body(smem, esrc_in, edst_in, bcnt, ebuf, blockIdx.x - GEMM_BLOCKS);
    }
}

__global__ __launch_bounds__(256) void gemm_kernel(
    const void* __restrict__ xin, const unsigned short* __restrict__ wt,
    const float* __restrict__ params, const unsigned int* __restrict__ flag,
    int mode, unsigned int* __restrict__ hh, float* __restrict__ el,
    float* __restrict__ er, unsigned int* __restrict__ gmax, int M) {
    __shared__ __align__(16) char smem[LDS_BYTES + 16];
    gemm_body(smem, xin, wt, params, flag, mode, hh, el, er, gmax, M, blockIdx.x);
}

// ---------- fused: single-pass (bounded-max) softmax agg + bias + LN + ELU ----------
// R6 body (best measured): quarter-wave edge split + fp16 h + edge-paired
// v_dot2_f32_f16. Three structural variants (R3/R6/R7) all land ~43 us —
// bound by the hh row-gather itself, so this is kept as-is.
template <bool LAST>
__global__ __launch_bounds__(256) void agg_ln_kernel(const int* __restrict__ offs,
                                                     const int* __restrict__ esrc,
                                                     const float* __restrict__ el,
                                                     const float* __restrict__ er,
                                                     const unsigned int* __restrict__ hh,
                                                     const float* __restrict__ params,
                                                     const unsigned int* __restrict__ gmax,
                                                     const unsigned int* __restrict__ flag,
                                                     unsigned int* __restrict__ x_next,
                                                     void* __restrict__ out) {
    int node = (blockIdx.x * 256 + threadIdx.x) >> 6;
    int lane = threadIdx.x & 63;
    if (node >= N_NODES) return;
    int e0 = offs[node], e1 = offs[node + 1];
    int d = e1 - e0;
    // producer role: slot loads edge b0+slot for head sh
    int sh = lane & 3;
    int slot = lane >> 2;
    // consumer role: quarter q handles edge-slots {q,4+q,8+q,12+q}; lane owns cols [l4*8, l4*8+8)
    int q = lane >> 4;
    int l4 = lane & 15;
    int hd = l4 >> 2;  // head of this lane's 8 columns
    float er_s = er[node * 4 + sh];
    float M = leaky(ord2f(gmax[sh]) + er_s);

    float lsum = 0.f;
    float a0 = 0.f, a1 = 0.f, a2 = 0.f, a3 = 0.f;
    float a4 = 0.f, a5 = 0.f, a6 = 0.f, a7 = 0.f;
    for (int b0 = 0; b0 < d; b0 += 16) {
        int idx = b0 + slot;
        float ex = 0.f;
        int s = 0;
        if (idx < d) {
            s = esrc[e0 + idx];
            ex = __expf(leaky(el[s * 4 + sh] + er_s) - M);
        }
        lsum += ex;
        __fp16 e16 = (__fp16)ex;
        unsigned int pk = ((unsigned int)s << 16)
                        | (unsigned int)__builtin_bit_cast(unsigned short, e16);
        // invalid edge slots broadcast pk==(s=0, ex=0): row-0 load cache-hot, dot*0.
#pragma unroll
        for (int jp = 0; jp < 2; ++jp) {
            unsigned int q1 = __shfl(pk, (jp * 8 + q) * 4 + hd);
            unsigned int q2 = __shfl(pk, (jp * 8 + 4 + q) * 4 + hd);
            int s1 = (int)(q1 >> 16);
            int s2 = (int)(q2 >> 16);
            uint4 p = *(const uint4*)(hh + s1 * 64 + l4 * 4);
            uint4 r = *(const uint4*)(hh + s2 * 64 + l4 * 4);
            unsigned int e2 = pair_lo(q1, q2);  // (ex1, ex2) as fp16x2
            a0 = dot2acc(pair_lo(p.x, r.x), e2, a0);
            a1 = dot2acc(pair_hi(p.x, r.x), e2, a1);
            a2 = dot2acc(pair_lo(p.y, r.y), e2, a2);
            a3 = dot2acc(pair_hi(p.y, r.y), e2, a3);
            a4 = dot2acc(pair_lo(p.z, r.z), e2, a4);
            a5 = dot2acc(pair_hi(p.z, r.z), e2, a5);
            a6 = dot2acc(pair_lo(p.w, r.w), e2, a6);
            a7 = dot2acc(pair_hi(p.w, r.w), e2, a7);
        }
    }
#pragma unroll
    for (int off = 4; off <= 32; off <<= 1) lsum += __shfl_xor(lsum, off);
    float l = __shfl(lsum, hd);
    // combine the 4 quarters (after this, all quarters hold identical sums)
    a0 += __shfl_xor(a0, 16); a0 += __shfl_xor(a0, 32);
    a1 += __shfl_xor(a1, 16); a1 += __shfl_xor(a1, 32);
    a2 += __shfl_xor(a2, 16); a2 += __shfl_xor(a2, 32);
    a3 += __shfl_xor(a3, 16); a3 += __shfl_xor(a3, 32);
    a4 += __shfl_xor(a4, 16); a4 += __shfl_xor(a4, 32);
    a5 += __shfl_xor(a5, 16); a5 += __shfl_xor(a5, 32);
    a6 += __shfl_xor(a6, 16); a6 += __shfl_xor(a6, 32);
    a7 += __shfl_xor(a7, 16); a7 += __shfl_xor(a7, 32);

    float inv = 1.f / fmaxf(l, 1e-9f);
    int c0 = l4 * 8;
    float4 ba = *(const float4*)(params + 16640 + c0);
    float4 bb = *(const float4*)(params + 16640 + c0 + 4);
    float v0 = fmaf(a0, inv, ba.x);
    float v1 = fmaf(a1, inv, ba.y);
    float v2 = fmaf(a2, inv, ba.z);
    float v3 = fmaf(a3, inv, ba.w);
    float v4 = fmaf(a4, inv, bb.x);
    float v5 = fmaf(a5, inv, bb.y);
    float v6 = fmaf(a6, inv, bb.z);
    float v7 = fmaf(a7, inv, bb.w);

    // interleaved sum / sum-of-squares reduction over the 16-lane group
    float s1 = (v0 + v1) + (v2 + v3) + (v4 + v5) + (v6 + v7);
    float s2 = (v0 * v0 + v1 * v1) + (v2 * v2 + v3 * v3)
             + (v4 * v4 + v5 * v5) + (v6 * v6 + v7 * v7);
#pragma unroll
    for (int off = 1; off <= 8; off <<= 1) {
        s1 += __shfl_xor(s1, off);
        s2 += __shfl_xor(s2, off);
    }
    float mu = s1 * (1.f / 128.f);
    float var = fmaxf(s2 * (1.f / 128.f) - mu * mu, 0.f);
    float rstd = rsqrtf(var + LN_EPS);
    float4 ga = *(const float4*)(params + 16768 + c0);
    float4 gb = *(const float4*)(params + 16768 + c0 + 4);
    float4 ea = *(const float4*)(params + 16896 + c0);
    float4 eb = *(const float4*)(params + 16896 + c0 + 4);
    float y0 = (v0 - mu) * rstd * ga.x + ea.x;
    float y1 = (v1 - mu) * rstd * ga.y + ea.y;
    float y2 = (v2 - mu) * rstd * ga.z + ea.z;
    float y3 = (v3 - mu) * rstd * ga.w + ea.w;
    float y4 = (v4 - mu) * rstd * gb.x + eb.x;
    float y5 = (v5 - mu) * rstd * gb.y + eb.y;
    float y6 = (v6 - mu) * rstd * gb.z + eb.z;
    float y7 = (v7 - mu) * rstd * gb.w + eb.w;
    // ELU via exp(y)-1 (cancellation err ~1e-8, well under absmax budget)
    y0 = y0 > 0.f ? y0 : (__expf(y0) - 1.f);
    y1 = y1 > 0.f ? y1 : (__expf(y1) - 1.f);
    y2 = y2 > 0.f ? y2 : (__expf(y2) - 1.f);
    y3 = y3 > 0.f ? y3 : (__expf(y3) - 1.f);
    y4 = y4 > 0.f ? y4 : (__expf(y4) - 1.f);
    y5 = y5 > 0.f ? y5 : (__expf(y5) - 1.f);
    y6 = y6 > 0.f ? y6 : (__expf(y6) - 1.f);
    y7 = y7 > 0.f ? y7 : (__expf(y7) - 1.f);

    if (q == 0) {
        if (LAST && !*flag) {
            *(float4*)((float*)out + node * 128 + c0) = make_float4(y0, y1, y2, y3);
            *(float4*)((float*)out + node * 128 + c0 + 4) = make_float4(y4, y5, y6, y7);
        } else {
            uint4 pk4;
            pk4.x = (unsigned int)(unsigned short)bfb(y0)
                  | ((unsigned int)(unsigned short)bfb(y1) << 16);
            pk4.y = (unsigned int)(unsigned short)bfb(y2)
                  | ((unsigned int)(unsigned short)bfb(y3) << 16);
            pk4.z = (unsigned int)(unsigned short)bfb(y4)
                  | ((unsigned int)(unsigned short)bfb(y5) << 16);
            pk4.w = (unsigned int)(unsigned short)bfb(y6)
                  | ((unsigned int)(unsigned short)bfb(y7) << 16);
            unsigned int* dst = LAST ? (unsigned int*)out : x_next;
            *(uint4*)(dst + node * 64 + l4 * 4) = pk4;
        }
    }
}

extern "C" void kernel_launch(void* const* d_in, const int* in_sizes, int n_in,
                              void* d_out, int out_size, void* d_ws, size_t ws_size,
                              hipStream_t stream) {
    const void* features = d_in[0];
    const int* src = (const int*)d_in[1];
    const int* dst = (const int*)d_in[2];

    char* w = (char*)d_ws;
    unsigned int* xbuf = (unsigned int*)w;                 // 12.8 MB (layer-2 input, packed bf16)
    unsigned int* hh = (unsigned int*)(w + 12800000);      // 12.8 MB (h fp16 packed)
    float* el = (float*)(w + 25600000);                    // 800 KB
    float* er = (float*)(w + 26400000);                    // 800 KB
    float* params0 = (float*)(w + 27200000);               // 68 KB
    float* params1 = params0 + PARAM_FLOATS;               // 68 KB
    unsigned short* wt0 = (unsigned short*)(w + 27337000); // 32 KB
    unsigned short* wt1 = wt0 + 16384;                     // 32 KB
    int* offs = (int*)(w + 27403000);                      // 50001 ints
    int* esrc = (int*)(w + 27604000);                      // 800000 ints
    int* bcnt  = (int*)(w + 30804992);                     // 196 ints
    unsigned int* flag  = (unsigned int*)(w + 30806848);
    unsigned int* gmax0 = (unsigned int*)(w + 30806912);
    unsigned int* gmax1 = (unsigned int*)(w + 30806976);
    unsigned int* ebuf = (unsigned int*)(w + 30807040);    // 196*6144*4 = 4.8 MB

    // K1: param cvt + one-time inits (flag, gmax, bcnt zero)
    cvt_params_kernel<<<2 * CVT_BLOCKS, 256, 0, stream>>>(
        d_in[3], d_in[4], d_in[5], d_in[6], d_in[7], d_in[8],
        d_in[9], d_in[10], d_in[11], d_in[12], d_in[13], d_in[14],
        params0, params1, wt0, wt1, flag, gmax0, gmax1, bcnt);

    // K2: gemm layer-1 fused with edge binning (independent work, one dispatch)
    gemm1_bin_kernel<<<GEMM_BLOCKS + BIN_BLOCKS, 256, 0, stream>>>(
        features, wt0, params0, flag, hh, el, er, gmax0, src, dst, bcnt, ebuf);

    // K3: CSR finalize
    csr_kernel<<<NBUCK, 256, 0, stream>>>(bcnt, ebuf, offs, esrc);

    // K4: agg+LN layer-1
    agg_ln_kernel<false><<<(N_NODES * 64 + 255) / 256, 256, 0, stream>>>(
        offs, esrc, el, er, hh, params0, gmax0, flag, xbuf, nullptr);

    // K5: gemm layer-2
    gemm_kernel<<<GEMM_BLOCKS, 256, 0, stream>>>(
        xbuf, wt1, params1, flag, 1, hh, el, er, gmax1, N_NODES);

    // K6: agg+LN layer-2 (writes final output)
    agg_ln_kernel<true><<<(N_NODES * 64 + 255) / 256, 256, 0, stream>>>(
        offs, esrc, el, er, hh, params1, gmax1, flag, nullptr, d_out);
}